// Round 1
// baseline (519.014 us; speedup 1.0000x reference)
//
#include <hip/hip_runtime.h>
#include <hip/hip_bf16.h>
#include <stdint.h>

#define T_ 2
#define N_ 4096
#define D_ 1024
#define E_ 8
#define O_ 1024

#define BM 128
#define BN 128
#define BK 32
#define LDK 40  // padded LDS row length in shorts: 80 B, 16B-aligned, 20-word stride -> 2-way (free)

typedef __attribute__((ext_vector_type(8))) short short8;
typedef __attribute__((ext_vector_type(4))) float f32x4;

__device__ inline unsigned short f2bf(float f) {
    union { float f; unsigned u; } v; v.f = f;
    unsigned r = v.u + 0x7fff + ((v.u >> 16) & 1);  // RNE
    return (unsigned short)(r >> 16);
}

// ---------------------------------------------------------------------------
// Kernel 1: gating (fp32 logits, top-2, gates, group scatter) + x -> bf16.
// One wave per token; 4 tokens per 256-thread block.
// ---------------------------------------------------------------------------
__global__ __launch_bounds__(256) void gate_kernel(
    const float* __restrict__ x, const float* __restrict__ Wg,
    unsigned short* __restrict__ xb,
    int* __restrict__ toklist, float* __restrict__ gatelist,
    int* __restrict__ counts)
{
    int wave = threadIdx.x >> 6;
    int lane = threadIdx.x & 63;
    int token = blockIdx.x * 4 + wave;          // 0..T*N-1
    int t = token >> 12;
    int n = token & (N_ - 1);

    const float* xrow = x + (size_t)token * D_;
    const float* wg   = Wg + (size_t)t * D_ * E_;

    float acc[E_];
#pragma unroll
    for (int e = 0; e < E_; ++e) acc[e] = 0.f;

#pragma unroll
    for (int i = 0; i < 4; ++i) {
        int d0 = i * 256 + lane * 4;
        float4 xv = *(const float4*)(xrow + d0);
        // fused bf16 conversion of x
        unsigned lo = f2bf(xv.x) | ((unsigned)f2bf(xv.y) << 16);
        unsigned hi = f2bf(xv.z) | ((unsigned)f2bf(xv.w) << 16);
        *(uint2*)(&xb[(size_t)token * D_ + d0]) = make_uint2(lo, hi);

        const float xs[4] = {xv.x, xv.y, xv.z, xv.w};
#pragma unroll
        for (int j = 0; j < 4; ++j) {
            int d = d0 + j;
            float4 w0 = *(const float4*)(wg + (size_t)d * E_);
            float4 w1 = *(const float4*)(wg + (size_t)d * E_ + 4);
            acc[0] += xs[j] * w0.x; acc[1] += xs[j] * w0.y;
            acc[2] += xs[j] * w0.z; acc[3] += xs[j] * w0.w;
            acc[4] += xs[j] * w1.x; acc[5] += xs[j] * w1.y;
            acc[6] += xs[j] * w1.z; acc[7] += xs[j] * w1.w;
        }
    }
    // butterfly reduce across the 64-lane wave
#pragma unroll
    for (int off = 1; off < 64; off <<= 1) {
#pragma unroll
        for (int e = 0; e < E_; ++e) acc[e] += __shfl_xor(acc[e], off, 64);
    }

    if (lane == 0) {
        // top-2, lowest-index-first on ties (matches jax.lax.top_k)
        float best = acc[0]; int bi = 0;
#pragma unroll
        for (int e = 1; e < E_; ++e) if (acc[e] > best) { best = acc[e]; bi = e; }
        float sec = -INFINITY; int si = 0;
#pragma unroll
        for (int e = 0; e < E_; ++e) if (e != bi && acc[e] > sec) { sec = acc[e]; si = e; }
        float s = best + sec + 1e-9f;
        float g0 = best / s;
        float g1 = sec  / s;
        int grp = t * E_ + bi;
        int p = atomicAdd(&counts[grp], 1);
        toklist[grp * N_ + p] = n;  gatelist[grp * N_ + p] = g0;
        grp = t * E_ + si;
        p = atomicAdd(&counts[grp], 1);
        toklist[grp * N_ + p] = n;  gatelist[grp * N_ + p] = g1;
    }
}

// ---------------------------------------------------------------------------
// Kernel 2: We fp32 [e][d][o] -> bf16 packed [ (e*8+o/128)*128 + o%128 ][ d ]
// (k-contiguous rows so GEMM B staging/frags are 16B vector ops).
// Thread handles 8 consecutive d at fixed (e,o): coalesced reads, 16B writes.
// ---------------------------------------------------------------------------
__global__ __launch_bounds__(256) void pack_kernel(
    const float* __restrict__ We, unsigned short* __restrict__ Wbp)
{
    int i = blockIdx.x * 256 + threadIdx.x;     // E*O*(D/8) = 1M threads
    int o  = i & (O_ - 1);
    int ed = i >> 10;
    int dg = ed & 127;        // d-group: d = dg*8 .. dg*8+7
    int e  = ed >> 7;

    const float* src = We + ((size_t)e * D_ + dg * 8) * O_ + o;
    unsigned short v[8];
#pragma unroll
    for (int j = 0; j < 8; ++j) v[j] = f2bf(src[(size_t)j * O_]);

    int ot = o >> 7, nn = o & 127;
    unsigned short* dst = Wbp + (((size_t)(e * 8 + ot) * 128 + nn) * D_ + dg * 8);
    unsigned u0 = v[0] | ((unsigned)v[1] << 16);
    unsigned u1 = v[2] | ((unsigned)v[3] << 16);
    unsigned u2 = v[4] | ((unsigned)v[5] << 16);
    unsigned u3 = v[6] | ((unsigned)v[7] << 16);
    *(uint4*)dst = make_uint4(u0, u1, u2, u3);
}

// ---------------------------------------------------------------------------
// Kernel 3: grouped GEMM. grid = (32 m-tiles, 8 o-tiles, 16 groups).
// 128x128 tile, BK=32, 4 waves x (4x4) mfma_f32_16x16x32_bf16.
// Epilogue scatters gate-weighted rows with fp32 atomicAdd (2 adds/elem).
// ---------------------------------------------------------------------------
__global__ __launch_bounds__(256) void moe_gemm(
    const unsigned short* __restrict__ xb,   // [T*N][D] bf16
    const unsigned short* __restrict__ Wbp,  // [(e*8+ot)*128+n][D] bf16
    const int* __restrict__ toklist, const float* __restrict__ gatelist,
    const int* __restrict__ counts, float* __restrict__ out)
{
    int g = blockIdx.z;                 // t*8 + e
    int t = g >> 3;
    int cnt = counts[g];
    int m0 = blockIdx.x * BM;
    if (m0 >= cnt) return;
    int ot = blockIdx.y;

    __shared__ unsigned short As[BM * LDK];
    __shared__ unsigned short Bs[BN * LDK];
    __shared__ int   tokS[BM];
    __shared__ float gateS[BM];

    int tid = threadIdx.x;
    if (tid < BM) {
        int r = m0 + tid;
        tokS[tid]  = (r < cnt) ? toklist[g * N_ + r]  : -1;
        gateS[tid] = (r < cnt) ? gatelist[g * N_ + r] : 0.f;
    }
    __syncthreads();

    // staging coords: thread -> (row, 16-short half)
    int sr = tid >> 1;
    int sc = (tid & 1) * 16;
    int tokr = tokS[sr];
    const unsigned short* arow =
        (tokr >= 0) ? (xb + ((size_t)(t * N_ + tokr)) * D_ + sc) : nullptr;
    const unsigned short* brow =
        Wbp + (((size_t)((g & 7) * 8 + ot) * 128 + sr) * D_ + sc);

    int wave = tid >> 6, lane = tid & 63;
    int wm = (wave & 1) * 64, wn = (wave >> 1) * 64;
    int fr = lane & 15, q = lane >> 4;

    f32x4 acc[4][4];
#pragma unroll
    for (int mi = 0; mi < 4; ++mi)
#pragma unroll
        for (int ni = 0; ni < 4; ++ni) acc[mi][ni] = (f32x4){0.f, 0.f, 0.f, 0.f};

    for (int k0 = 0; k0 < D_; k0 += BK) {
        uint4 av0 = make_uint4(0, 0, 0, 0), av1 = make_uint4(0, 0, 0, 0);
        if (tokr >= 0) {
            av0 = *(const uint4*)(arow + k0);
            av1 = *(const uint4*)(arow + k0 + 8);
        }
        uint4 bv0 = *(const uint4*)(brow + k0);
        uint4 bv1 = *(const uint4*)(brow + k0 + 8);
        __syncthreads();   // previous iteration's frag reads done
        *(uint4*)(&As[sr * LDK + sc])     = av0;
        *(uint4*)(&As[sr * LDK + sc + 8]) = av1;
        *(uint4*)(&Bs[sr * LDK + sc])     = bv0;
        *(uint4*)(&Bs[sr * LDK + sc + 8]) = bv1;
        __syncthreads();

        short8 af[4], bf[4];
#pragma unroll
        for (int mi = 0; mi < 4; ++mi)
            af[mi] = *(const short8*)(&As[(wm + mi * 16 + fr) * LDK + q * 8]);
#pragma unroll
        for (int ni = 0; ni < 4; ++ni)
            bf[ni] = *(const short8*)(&Bs[(wn + ni * 16 + fr) * LDK + q * 8]);
#pragma unroll
        for (int mi = 0; mi < 4; ++mi)
#pragma unroll
            for (int ni = 0; ni < 4; ++ni)
                acc[mi][ni] = __builtin_amdgcn_mfma_f32_16x16x32_bf16(
                    af[mi], bf[ni], acc[mi][ni], 0, 0, 0);
    }

    // epilogue: C/D layout col = lane&15, row = q*4 + reg  [m89/m91]
    float* outb = out + (size_t)t * N_ * O_;
    int ncol = ot * 128 + wn + fr;
#pragma unroll
    for (int mi = 0; mi < 4; ++mi) {
#pragma unroll
        for (int r = 0; r < 4; ++r) {
            int ml = wm + mi * 16 + q * 4 + r;
            int tok = tokS[ml];
            if (tok >= 0) {
                float gate = gateS[ml];
#pragma unroll
                for (int ni = 0; ni < 4; ++ni)
                    atomicAdd(&outb[(size_t)tok * O_ + ncol + ni * 16],
                              gate * acc[mi][ni][r]);
            }
        }
    }
}

// ---------------------------------------------------------------------------
extern "C" void kernel_launch(void* const* d_in, const int* in_sizes, int n_in,
                              void* d_out, int out_size, void* d_ws, size_t ws_size,
                              hipStream_t stream)
{
    const float* x  = (const float*)d_in[0];
    const float* Wg = (const float*)d_in[1];
    const float* We = (const float*)d_in[2];
    float* out = (float*)d_out;

    char* ws = (char*)d_ws;
    unsigned short* xb   = (unsigned short*)(ws);               // 16,777,216 B
    unsigned short* Wbp  = (unsigned short*)(ws + 16777216);    // 16,777,216 B
    int*   toklist       = (int*)  (ws + 33554432);             //    262,144 B
    float* gatelist      = (float*)(ws + 33816576);             //    262,144 B
    int*   counts        = (int*)  (ws + 34078720);             //         64 B

    hipMemsetAsync(out, 0, (size_t)T_ * N_ * O_ * sizeof(float), stream);
    hipMemsetAsync(counts, 0, T_ * E_ * sizeof(int), stream);

    gate_kernel<<<(T_ * N_) / 4, 256, 0, stream>>>(x, Wg, xb, toklist, gatelist, counts);
    pack_kernel<<<(E_ * O_ * (D_ / 8)) / 256, 256, 0, stream>>>(We, Wbp);
    moe_gemm<<<dim3(N_ / BM, O_ / BN, T_ * E_), 256, 0, stream>>>(
        xb, Wbp, toklist, gatelist, counts, out);
}

// Round 2
// 393.432 us; speedup vs baseline: 1.3192x; 1.3192x over previous
//
#include <hip/hip_runtime.h>
#include <hip/hip_bf16.h>
#include <stdint.h>

#define T_ 2
#define N_ 4096
#define D_ 1024
#define E_ 8
#define O_ 1024

#define BM 128
#define BN 128
#define BK 32   // K elements per LDS tile; unpadded rows (global_load_lds needs base+lane*16)

typedef __attribute__((ext_vector_type(8))) short short8;
typedef __attribute__((ext_vector_type(4))) float f32x4;

#define AS1 __attribute__((address_space(1)))
#define AS3 __attribute__((address_space(3)))

// async global->LDS, 16B per lane; LDS dest = base + lane*16 (wave-uniform base)
__device__ inline void gld16(const unsigned short* g, unsigned short* l) {
    __builtin_amdgcn_global_load_lds((const AS1 unsigned int*)g,
                                     (AS3 unsigned int*)l, 16, 0, 0);
}

__device__ inline unsigned short f2bf(float f) {
    union { float f; unsigned u; } v; v.f = f;
    unsigned r = v.u + 0x7fff + ((v.u >> 16) & 1);  // RNE
    return (unsigned short)(r >> 16);
}

// ---------------------------------------------------------------------------
// Kernel 1: gating (fp32 logits, top-2, gates, group scatter) + x -> bf16.
// One wave per token; 4 tokens per 256-thread block.
// ---------------------------------------------------------------------------
__global__ __launch_bounds__(256) void gate_kernel(
    const float* __restrict__ x, const float* __restrict__ Wg,
    unsigned short* __restrict__ xb,
    int* __restrict__ toklist, float* __restrict__ gatelist,
    int* __restrict__ counts)
{
    int wave = threadIdx.x >> 6;
    int lane = threadIdx.x & 63;
    int token = blockIdx.x * 4 + wave;          // 0..T*N-1
    int t = token >> 12;
    int n = token & (N_ - 1);

    const float* xrow = x + (size_t)token * D_;
    const float* wg   = Wg + (size_t)t * D_ * E_;

    float acc[E_];
#pragma unroll
    for (int e = 0; e < E_; ++e) acc[e] = 0.f;

#pragma unroll
    for (int i = 0; i < 4; ++i) {
        int d0 = i * 256 + lane * 4;
        float4 xv = *(const float4*)(xrow + d0);
        unsigned lo = f2bf(xv.x) | ((unsigned)f2bf(xv.y) << 16);
        unsigned hi = f2bf(xv.z) | ((unsigned)f2bf(xv.w) << 16);
        *(uint2*)(&xb[(size_t)token * D_ + d0]) = make_uint2(lo, hi);

        const float xs[4] = {xv.x, xv.y, xv.z, xv.w};
#pragma unroll
        for (int j = 0; j < 4; ++j) {
            int d = d0 + j;
            float4 w0 = *(const float4*)(wg + (size_t)d * E_);
            float4 w1 = *(const float4*)(wg + (size_t)d * E_ + 4);
            acc[0] += xs[j] * w0.x; acc[1] += xs[j] * w0.y;
            acc[2] += xs[j] * w0.z; acc[3] += xs[j] * w0.w;
            acc[4] += xs[j] * w1.x; acc[5] += xs[j] * w1.y;
            acc[6] += xs[j] * w1.z; acc[7] += xs[j] * w1.w;
        }
    }
#pragma unroll
    for (int off = 1; off < 64; off <<= 1) {
#pragma unroll
        for (int e = 0; e < E_; ++e) acc[e] += __shfl_xor(acc[e], off, 64);
    }

    if (lane == 0) {
        // top-2, lowest-index-first on ties (matches jax.lax.top_k)
        float best = acc[0]; int bi = 0;
#pragma unroll
        for (int e = 1; e < E_; ++e) if (acc[e] > best) { best = acc[e]; bi = e; }
        float sec = -INFINITY; int si = 0;
#pragma unroll
        for (int e = 0; e < E_; ++e) if (e != bi && acc[e] > sec) { sec = acc[e]; si = e; }
        float s = best + sec + 1e-9f;
        float g0 = best / s;
        float g1 = sec  / s;
        int grp = t * E_ + bi;
        int p = atomicAdd(&counts[grp], 1);
        toklist[grp * N_ + p] = n;  gatelist[grp * N_ + p] = g0;
        grp = t * E_ + si;
        p = atomicAdd(&counts[grp], 1);
        toklist[grp * N_ + p] = n;  gatelist[grp * N_ + p] = g1;
    }
}

// ---------------------------------------------------------------------------
// Kernel 2: We fp32 [e][d][o] -> bf16 packed [(e*8+o/128)*128 + o%128][d].
// LDS transpose: coalesced 256B-segment reads AND writes (round-1 version
// scattered 16B writes at 2KB stride).
// Block = 256 threads, tile = 64 o x 128 d. Grid = E * (O/64) * (D/128).
// ---------------------------------------------------------------------------
__global__ __launch_bounds__(256) void pack_kernel(
    const float* __restrict__ We, unsigned short* __restrict__ Wbp)
{
    __shared__ __align__(16) unsigned short P[64 * 136];  // 136: 16B-aligned padded row

    int b = blockIdx.x;
    int e  = b >> 7;
    int oy = (b & 127) >> 3;   // 0..15
    int dz = b & 7;            // 0..7
    int o0 = oy * 64, d0 = dz * 128;
    int tid = threadIdx.x;

#pragma unroll
    for (int r = 0; r < 32; ++r) {
        int lin = r * 256 + tid;
        int dd = lin >> 6, oo = lin & 63;
        P[oo * 136 + dd] = f2bf(We[((size_t)(e * D_ + d0 + dd)) * O_ + o0 + oo]);
    }
    __syncthreads();

#pragma unroll
    for (int w = 0; w < 4; ++w) {
        int ci = w * 256 + tid;      // 1024 16B-chunks
        int oo = ci >> 4, dc = ci & 15;
        uint4 v = *(const uint4*)&P[oo * 136 + dc * 8];
        int o = o0 + oo;
        int ot = o >> 7, nn = o & 127;
        unsigned short* dst =
            Wbp + ((size_t)((e * 8 + ot) * 128 + nn)) * D_ + d0 + dc * 8;
        *(uint4*)dst = v;
    }
}

// ---------------------------------------------------------------------------
// Kernel 3: grouped GEMM, m97 structure. 128x128x32 tile, 4 waves x (4x4)
// mfma_f32_16x16x32_bf16, global_load_lds width=16, unpadded [row][32] LDS.
// XCD swizzle: m-tiles sharing a B-tile land on the same XCD's L2.
// Epilogue: gate-weighted fp32 atomicAdd (exactly 2 adds per out element).
// ---------------------------------------------------------------------------
__global__ __launch_bounds__(256) void moe_gemm(
    const unsigned short* __restrict__ xb,   // [T*N][D] bf16
    const unsigned short* __restrict__ Wbp,  // [(e*8+ot)*128+n][D] bf16
    const int* __restrict__ toklist, const float* __restrict__ gatelist,
    const int* __restrict__ counts, float* __restrict__ out)
{
    // flat id -> (m-tile, o-tile, group) with XCD affinity: xcd = lin & 7
    int lin = blockIdx.x + (blockIdx.y << 5) + (blockIdx.z << 8);  // 0..4095
    int xcd = lin & 7, slot = lin >> 3;       // 512 slots per XCD
    int mt = slot & 31;
    int pr = xcd * 16 + (slot >> 5);          // 0..127 = (ot, g) pair
    int ot = pr & 7;
    int g  = pr >> 3;                         // t*8 + e
    int t  = g >> 3;

    int cnt = counts[g];
    int m0 = mt * BM;
    if (m0 >= cnt) return;

    __shared__ __align__(16) unsigned short As[BM * 32];  // 8 KB
    __shared__ __align__(16) unsigned short Bs[BN * 32];  // 8 KB
    __shared__ int   tokS[BM];
    __shared__ float gateS[BM];

    int tid = threadIdx.x;
    if (tid < BM) {
        int r = m0 + tid;
        tokS[tid]  = (r < cnt) ? toklist[g * N_ + r]  : -1;
        gateS[tid] = (r < cnt) ? gatelist[g * N_ + r] : 0.f;
    }
    __syncthreads();

    int wave = tid >> 6, lane = tid & 63;
    // staging: wave w loads chunks 2w, 2w+1 of A and of B (16 rows/chunk)
    int lr = lane >> 2;          // row within chunk
    int lc = (lane & 3) * 8;     // short offset within row
    int c0 = wave * 2, c1 = c0 + 1;
    int ar0 = c0 * 16 + lr, ar1 = c1 * 16 + lr;
    int tok0 = max(tokS[ar0], 0), tok1 = max(tokS[ar1], 0);  // clamped: junk rows masked in epilogue
    const unsigned short* ag0 = xb + ((size_t)(t * N_ + tok0)) * D_ + lc;
    const unsigned short* ag1 = xb + ((size_t)(t * N_ + tok1)) * D_ + lc;
    const unsigned short* wb  = Wbp + ((size_t)((g & 7) * 8 + ot) * 128) * D_;
    const unsigned short* bg0 = wb + (size_t)ar0 * D_ + lc;
    const unsigned short* bg1 = wb + (size_t)ar1 * D_ + lc;
    unsigned short* la0 = &As[c0 * 16 * 32];  // wave-uniform LDS bases
    unsigned short* la1 = &As[c1 * 16 * 32];
    unsigned short* lb0 = &Bs[c0 * 16 * 32];
    unsigned short* lb1 = &Bs[c1 * 16 * 32];

    int wm = (wave & 1) * 64, wn = (wave >> 1) * 64;
    int fr = lane & 15, q = lane >> 4;

    f32x4 acc[4][4];
#pragma unroll
    for (int mi = 0; mi < 4; ++mi)
#pragma unroll
        for (int ni = 0; ni < 4; ++ni) acc[mi][ni] = (f32x4){0.f, 0.f, 0.f, 0.f};

    for (int k0 = 0; k0 < D_; k0 += BK) {
        gld16(ag0 + k0, la0);
        gld16(ag1 + k0, la1);
        gld16(bg0 + k0, lb0);
        gld16(bg1 + k0, lb1);
        __syncthreads();   // drains vmcnt (loads landed) + all waves staged

        short8 af[4], bf[4];
#pragma unroll
        for (int mi = 0; mi < 4; ++mi)
            af[mi] = *(const short8*)(&As[(wm + mi * 16 + fr) * 32 + q * 8]);
#pragma unroll
        for (int ni = 0; ni < 4; ++ni)
            bf[ni] = *(const short8*)(&Bs[(wn + ni * 16 + fr) * 32 + q * 8]);
#pragma unroll
        for (int mi = 0; mi < 4; ++mi)
#pragma unroll
            for (int ni = 0; ni < 4; ++ni)
                acc[mi][ni] = __builtin_amdgcn_mfma_f32_16x16x32_bf16(
                    af[mi], bf[ni], acc[mi][ni], 0, 0, 0);
        __syncthreads();   // frags consumed before next stage overwrites
    }

    // epilogue: C/D layout col = lane&15, row = q*4 + reg  [m89/m91]
    float* outb = out + (size_t)t * N_ * O_;
    int ncol = ot * 128 + wn + fr;
#pragma unroll
    for (int mi = 0; mi < 4; ++mi) {
#pragma unroll
        for (int r = 0; r < 4; ++r) {
            int ml = wm + mi * 16 + q * 4 + r;
            int tok = tokS[ml];
            if (tok >= 0) {
                float gate = gateS[ml];
#pragma unroll
                for (int ni = 0; ni < 4; ++ni)
                    atomicAdd(&outb[(size_t)tok * O_ + ncol + ni * 16],
                              gate * acc[mi][ni][r]);
            }
        }
    }
}

// ---------------------------------------------------------------------------
extern "C" void kernel_launch(void* const* d_in, const int* in_sizes, int n_in,
                              void* d_out, int out_size, void* d_ws, size_t ws_size,
                              hipStream_t stream)
{
    const float* x  = (const float*)d_in[0];
    const float* Wg = (const float*)d_in[1];
    const float* We = (const float*)d_in[2];
    float* out = (float*)d_out;

    char* ws = (char*)d_ws;
    unsigned short* xb   = (unsigned short*)(ws);               // 16,777,216 B
    unsigned short* Wbp  = (unsigned short*)(ws + 16777216);    // 16,777,216 B
    int*   toklist       = (int*)  (ws + 33554432);             //    262,144 B
    float* gatelist      = (float*)(ws + 33816576);             //    262,144 B
    int*   counts        = (int*)  (ws + 34078720);             //         64 B

    hipMemsetAsync(out, 0, (size_t)T_ * N_ * O_ * sizeof(float), stream);
    hipMemsetAsync(counts, 0, T_ * E_ * sizeof(int), stream);

    gate_kernel<<<(T_ * N_) / 4, 256, 0, stream>>>(x, Wg, xb, toklist, gatelist, counts);
    pack_kernel<<<E_ * (O_ / 64) * (D_ / 128), 256, 0, stream>>>(We, Wbp);
    moe_gemm<<<dim3(N_ / BM, O_ / BN, T_ * E_), 256, 0, stream>>>(
        xb, Wbp, toklist, gatelist, counts, out);
}

// Round 3
// 386.930 us; speedup vs baseline: 1.3414x; 1.0168x over previous
//
#include <hip/hip_runtime.h>
#include <hip/hip_bf16.h>
#include <stdint.h>

#define T_ 2
#define N_ 4096
#define D_ 1024
#define E_ 8
#define O_ 1024

#define BM 128
#define BN 128
#define BK 32   // K elements per LDS tile; unpadded rows (global_load_lds needs base+lane*16)

typedef __attribute__((ext_vector_type(8))) short short8;
typedef __attribute__((ext_vector_type(4))) float f32x4;

#define AS1 __attribute__((address_space(1)))
#define AS3 __attribute__((address_space(3)))

// async global->LDS, 16B per lane; LDS dest = base + lane*16 (wave-uniform base)
__device__ inline void gld16(const unsigned short* g, unsigned short* l) {
    __builtin_amdgcn_global_load_lds((const AS1 unsigned int*)g,
                                     (AS3 unsigned int*)l, 16, 0, 0);
}

__device__ inline unsigned short f2bf(float f) {
    union { float f; unsigned u; } v; v.f = f;
    unsigned r = v.u + 0x7fff + ((v.u >> 16) & 1);  // RNE
    return (unsigned short)(r >> 16);
}

// ---------------------------------------------------------------------------
// Kernel 1: gating + x->bf16. Rewritten round 3: Wg staged TRANSPOSED in LDS
// (round-2 version did per-lane 128B-stride global Wg loads -> 64 cache lines
// per wave-load, latency-serialized at VGPR=36 -> 200 us).
// Block = 256 threads = 4 waves = 4 tokens (all same t). Grid = T*N/4.
// ---------------------------------------------------------------------------
__global__ __launch_bounds__(256) void gate_kernel(
    const float* __restrict__ x, const float* __restrict__ Wg,
    unsigned short* __restrict__ xb,
    int* __restrict__ toklist, float* __restrict__ gatelist,
    int* __restrict__ counts)
{
    __shared__ __align__(16) float WgT[E_][D_];   // 32 KB, conflict-free lane reads

    int tid = threadIdx.x;
    int wave = tid >> 6, lane = tid & 63;
    int token0 = blockIdx.x * 4;
    int t = token0 >> 12;                 // 4 consecutive tokens share t
    const float* wgb = Wg + (size_t)t * D_ * E_;

    // fill: coalesced float4 global reads; LDS scatter is 2-way/bank (free)
#pragma unroll
    for (int r = 0; r < 8; ++r) {
        int f = r * 1024 + tid * 4;       // flat Wg index; (d=f>>3, e=f&7)
        float4 v = *(const float4*)(wgb + f);
        WgT[f & 7][f >> 3]             = v.x;
        WgT[(f + 1) & 7][(f + 1) >> 3] = v.y;
        WgT[(f + 2) & 7][(f + 2) >> 3] = v.z;
        WgT[(f + 3) & 7][(f + 3) >> 3] = v.w;
    }
    __syncthreads();

    int token = token0 + wave;
    int n = token & (N_ - 1);
    const float* xrow = x + (size_t)token * D_;

    // all 4 x chunks issued up front for ILP
    float4 xv[4];
#pragma unroll
    for (int c = 0; c < 4; ++c)
        xv[c] = *(const float4*)(xrow + c * 256 + lane * 4);

    float acc[E_] = {0.f, 0.f, 0.f, 0.f, 0.f, 0.f, 0.f, 0.f};
#pragma unroll
    for (int c = 0; c < 4; ++c) {
        int d0 = c * 256 + lane * 4;
        unsigned lo = f2bf(xv[c].x) | ((unsigned)f2bf(xv[c].y) << 16);
        unsigned hi = f2bf(xv[c].z) | ((unsigned)f2bf(xv[c].w) << 16);
        *(uint2*)(&xb[(size_t)token * D_ + d0]) = make_uint2(lo, hi);
#pragma unroll
        for (int e = 0; e < E_; ++e) {
            float4 w = *(const float4*)(&WgT[e][d0]);   // contiguous across lanes
            acc[e] += xv[c].x * w.x + xv[c].y * w.y + xv[c].z * w.z + xv[c].w * w.w;
        }
    }
#pragma unroll
    for (int off = 1; off < 64; off <<= 1) {
#pragma unroll
        for (int e = 0; e < E_; ++e) acc[e] += __shfl_xor(acc[e], off, 64);
    }

    if (lane == 0) {
        // top-2, lowest-index-first on ties (matches jax.lax.top_k)
        float best = acc[0]; int bi = 0;
#pragma unroll
        for (int e = 1; e < E_; ++e) if (acc[e] > best) { best = acc[e]; bi = e; }
        float sec = -INFINITY; int si = 0;
#pragma unroll
        for (int e = 0; e < E_; ++e) if (e != bi && acc[e] > sec) { sec = acc[e]; si = e; }
        float s = best + sec + 1e-9f;
        float g0 = best / s;
        float g1 = sec  / s;
        int grp = t * E_ + bi;
        int p = atomicAdd(&counts[grp], 1);
        toklist[grp * N_ + p] = n;  gatelist[grp * N_ + p] = g0;
        grp = t * E_ + si;
        p = atomicAdd(&counts[grp], 1);
        toklist[grp * N_ + p] = n;  gatelist[grp * N_ + p] = g1;
    }
}

// ---------------------------------------------------------------------------
// Kernel 2: We fp32 [e][d][o] -> bf16 packed [(e*8+o/128)*128 + o%128][d].
// LDS transpose: coalesced 256B-segment reads AND writes.
// Block = 256 threads, tile = 64 o x 128 d. Grid = E * (O/64) * (D/128).
// ---------------------------------------------------------------------------
__global__ __launch_bounds__(256) void pack_kernel(
    const float* __restrict__ We, unsigned short* __restrict__ Wbp)
{
    __shared__ __align__(16) unsigned short P[64 * 136];  // 136: 16B-aligned padded row

    int b = blockIdx.x;
    int e  = b >> 7;
    int oy = (b & 127) >> 3;   // 0..15
    int dz = b & 7;            // 0..7
    int o0 = oy * 64, d0 = dz * 128;
    int tid = threadIdx.x;

#pragma unroll
    for (int r = 0; r < 32; ++r) {
        int lin = r * 256 + tid;
        int dd = lin >> 6, oo = lin & 63;
        P[oo * 136 + dd] = f2bf(We[((size_t)(e * D_ + d0 + dd)) * O_ + o0 + oo]);
    }
    __syncthreads();

#pragma unroll
    for (int w = 0; w < 4; ++w) {
        int ci = w * 256 + tid;      // 1024 16B-chunks
        int oo = ci >> 4, dc = ci & 15;
        uint4 v = *(const uint4*)&P[oo * 136 + dc * 8];
        int o = o0 + oo;
        int ot = o >> 7, nn = o & 127;
        unsigned short* dst =
            Wbp + ((size_t)((e * 8 + ot) * 128 + nn)) * D_ + d0 + dc * 8;
        *(uint4*)dst = v;
    }
}

// ---------------------------------------------------------------------------
// Kernel 3: grouped GEMM, m97 structure. 128x128x32 tile, 4 waves x (4x4)
// mfma_f32_16x16x32_bf16, global_load_lds width=16, unpadded [row][32] LDS.
// XCD swizzle: m-tiles sharing a B-tile land on the same XCD's L2.
// Epilogue: gate-weighted fp32 atomicAdd (exactly 2 adds per out element).
// ---------------------------------------------------------------------------
__global__ __launch_bounds__(256) void moe_gemm(
    const unsigned short* __restrict__ xb,   // [T*N][D] bf16
    const unsigned short* __restrict__ Wbp,  // [(e*8+ot)*128+n][D] bf16
    const int* __restrict__ toklist, const float* __restrict__ gatelist,
    const int* __restrict__ counts, float* __restrict__ out)
{
    // flat id -> (m-tile, o-tile, group) with XCD affinity: xcd = lin & 7
    int lin = blockIdx.x + (blockIdx.y << 5) + (blockIdx.z << 8);  // 0..4095
    int xcd = lin & 7, slot = lin >> 3;       // 512 slots per XCD
    int mt = slot & 31;
    int pr = xcd * 16 + (slot >> 5);          // 0..127 = (ot, g) pair
    int ot = pr & 7;
    int g  = pr >> 3;                         // t*8 + e
    int t  = g >> 3;

    int cnt = counts[g];
    int m0 = mt * BM;
    if (m0 >= cnt) return;

    __shared__ __align__(16) unsigned short As[BM * 32];  // 8 KB
    __shared__ __align__(16) unsigned short Bs[BN * 32];  // 8 KB
    __shared__ int   tokS[BM];
    __shared__ float gateS[BM];

    int tid = threadIdx.x;
    if (tid < BM) {
        int r = m0 + tid;
        tokS[tid]  = (r < cnt) ? toklist[g * N_ + r]  : -1;
        gateS[tid] = (r < cnt) ? gatelist[g * N_ + r] : 0.f;
    }
    __syncthreads();

    int wave = tid >> 6, lane = tid & 63;
    // staging: wave w loads chunks 2w, 2w+1 of A and of B (16 rows/chunk)
    int lr = lane >> 2;          // row within chunk
    int lc = (lane & 3) * 8;     // short offset within row
    int c0 = wave * 2, c1 = c0 + 1;
    int ar0 = c0 * 16 + lr, ar1 = c1 * 16 + lr;
    int tok0 = max(tokS[ar0], 0), tok1 = max(tokS[ar1], 0);  // junk rows masked in epilogue
    const unsigned short* ag0 = xb + ((size_t)(t * N_ + tok0)) * D_ + lc;
    const unsigned short* ag1 = xb + ((size_t)(t * N_ + tok1)) * D_ + lc;
    const unsigned short* wb  = Wbp + ((size_t)((g & 7) * 8 + ot) * 128) * D_;
    const unsigned short* bg0 = wb + (size_t)ar0 * D_ + lc;
    const unsigned short* bg1 = wb + (size_t)ar1 * D_ + lc;
    unsigned short* la0 = &As[c0 * 16 * 32];  // wave-uniform LDS bases
    unsigned short* la1 = &As[c1 * 16 * 32];
    unsigned short* lb0 = &Bs[c0 * 16 * 32];
    unsigned short* lb1 = &Bs[c1 * 16 * 32];

    int wm = (wave & 1) * 64, wn = (wave >> 1) * 64;
    int fr = lane & 15, q = lane >> 4;

    f32x4 acc[4][4];
#pragma unroll
    for (int mi = 0; mi < 4; ++mi)
#pragma unroll
        for (int ni = 0; ni < 4; ++ni) acc[mi][ni] = (f32x4){0.f, 0.f, 0.f, 0.f};

    for (int k0 = 0; k0 < D_; k0 += BK) {
        gld16(ag0 + k0, la0);
        gld16(ag1 + k0, la1);
        gld16(bg0 + k0, lb0);
        gld16(bg1 + k0, lb1);
        __syncthreads();   // drains vmcnt (loads landed) + all waves staged

        short8 af[4], bf[4];
#pragma unroll
        for (int mi = 0; mi < 4; ++mi)
            af[mi] = *(const short8*)(&As[(wm + mi * 16 + fr) * 32 + q * 8]);
#pragma unroll
        for (int ni = 0; ni < 4; ++ni)
            bf[ni] = *(const short8*)(&Bs[(wn + ni * 16 + fr) * 32 + q * 8]);
#pragma unroll
        for (int mi = 0; mi < 4; ++mi)
#pragma unroll
            for (int ni = 0; ni < 4; ++ni)
                acc[mi][ni] = __builtin_amdgcn_mfma_f32_16x16x32_bf16(
                    af[mi], bf[ni], acc[mi][ni], 0, 0, 0);
        __syncthreads();   // frags consumed before next stage overwrites
    }

    // epilogue: C/D layout col = lane&15, row = q*4 + reg  [m89/m91]
    float* outb = out + (size_t)t * N_ * O_;
    int ncol = ot * 128 + wn + fr;
#pragma unroll
    for (int mi = 0; mi < 4; ++mi) {
#pragma unroll
        for (int r = 0; r < 4; ++r) {
            int ml = wm + mi * 16 + q * 4 + r;
            int tok = tokS[ml];
            if (tok >= 0) {
                float gate = gateS[ml];
#pragma unroll
                for (int ni = 0; ni < 4; ++ni)
                    atomicAdd(&outb[(size_t)tok * O_ + ncol + ni * 16],
                              gate * acc[mi][ni][r]);
            }
        }
    }
}

// ---------------------------------------------------------------------------
extern "C" void kernel_launch(void* const* d_in, const int* in_sizes, int n_in,
                              void* d_out, int out_size, void* d_ws, size_t ws_size,
                              hipStream_t stream)
{
    const float* x  = (const float*)d_in[0];
    const float* Wg = (const float*)d_in[1];
    const float* We = (const float*)d_in[2];
    float* out = (float*)d_out;

    char* ws = (char*)d_ws;
    unsigned short* xb   = (unsigned short*)(ws);               // 16,777,216 B
    unsigned short* Wbp  = (unsigned short*)(ws + 16777216);    // 16,777,216 B
    int*   toklist       = (int*)  (ws + 33554432);             //    262,144 B
    float* gatelist      = (float*)(ws + 33816576);             //    262,144 B
    int*   counts        = (int*)  (ws + 34078720);             //         64 B

    hipMemsetAsync(out, 0, (size_t)T_ * N_ * O_ * sizeof(float), stream);
    hipMemsetAsync(counts, 0, T_ * E_ * sizeof(int), stream);

    gate_kernel<<<(T_ * N_) / 4, 256, 0, stream>>>(x, Wg, xb, toklist, gatelist, counts);
    pack_kernel<<<E_ * (O_ / 64) * (D_ / 128), 256, 0, stream>>>(We, Wbp);
    moe_gemm<<<dim3(N_ / BM, O_ / BN, T_ * E_), 256, 0, stream>>>(
        xb, Wbp, toklist, gatelist, counts, out);
}

// Round 4
// 217.992 us; speedup vs baseline: 2.3809x; 1.7750x over previous
//
#include <hip/hip_runtime.h>
#include <hip/hip_bf16.h>
#include <stdint.h>

#define T_ 2
#define N_ 4096
#define D_ 1024
#define E_ 8
#define O_ 1024

#define BM 128
#define BN 128
#define BK 32   // K elements per LDS tile; unpadded rows (global_load_lds needs base+lane*16)

typedef __attribute__((ext_vector_type(8))) short short8;
typedef __attribute__((ext_vector_type(4))) float f32x4;

#define AS1 __attribute__((address_space(1)))
#define AS3 __attribute__((address_space(3)))

// async global->LDS, 16B per lane; LDS dest = base + lane*16 (wave-uniform base)
__device__ inline void gld16(const unsigned short* g, unsigned short* l) {
    __builtin_amdgcn_global_load_lds((const AS1 unsigned int*)g,
                                     (AS3 unsigned int*)l, 16, 0, 0);
}

__device__ inline unsigned short f2bf(float f) {
    union { float f; unsigned u; } v; v.f = f;
    unsigned r = v.u + 0x7fff + ((v.u >> 16) & 1);  // RNE
    return (unsigned short)(r >> 16);
}

// ---------------------------------------------------------------------------
// Kernel 1: gating + x->bf16. Round 4: NO ATOMICS (rounds 1-3 spent ~195 us
// serializing 16K atomicAdds on one 64B cache line across 8 XCDs). Writes
// per-token route/gates; compaction moved to build_lists. 16 tokens/block
// (4 per wave) to amortize the 32 KB Wg->LDS fill. Grid = T*N/16.
// ---------------------------------------------------------------------------
__global__ __launch_bounds__(256) void gate_kernel(
    const float* __restrict__ x, const float* __restrict__ Wg,
    unsigned short* __restrict__ xb,
    int* __restrict__ route, float2* __restrict__ gpair)
{
    __shared__ __align__(16) float WgT[E_][D_];   // 32 KB

    int tid = threadIdx.x;
    int wave = tid >> 6, lane = tid & 63;
    int token0 = blockIdx.x * 16;
    int t = token0 >> 12;                 // 16 consecutive tokens share t
    const float* wgb = Wg + (size_t)t * D_ * E_;

    // fill: coalesced float4 global reads; LDS scatter is 2-way/bank (free)
#pragma unroll
    for (int r = 0; r < 8; ++r) {
        int f = r * 1024 + tid * 4;       // flat Wg index; (d=f>>3, e=f&7)
        float4 v = *(const float4*)(wgb + f);
        WgT[f & 7][f >> 3]             = v.x;
        WgT[(f + 1) & 7][(f + 1) >> 3] = v.y;
        WgT[(f + 2) & 7][(f + 2) >> 3] = v.z;
        WgT[(f + 3) & 7][(f + 3) >> 3] = v.w;
    }
    __syncthreads();

    for (int tl = 0; tl < 4; ++tl) {
        int token = token0 + wave * 4 + tl;
        const float* xrow = x + (size_t)token * D_;

        float4 xv[4];
#pragma unroll
        for (int c = 0; c < 4; ++c)
            xv[c] = *(const float4*)(xrow + c * 256 + lane * 4);

        float acc[E_] = {0.f, 0.f, 0.f, 0.f, 0.f, 0.f, 0.f, 0.f};
#pragma unroll
        for (int c = 0; c < 4; ++c) {
            int d0 = c * 256 + lane * 4;
            unsigned lo = f2bf(xv[c].x) | ((unsigned)f2bf(xv[c].y) << 16);
            unsigned hi = f2bf(xv[c].z) | ((unsigned)f2bf(xv[c].w) << 16);
            *(uint2*)(&xb[(size_t)token * D_ + d0]) = make_uint2(lo, hi);
#pragma unroll
            for (int e = 0; e < E_; ++e) {
                float4 w = *(const float4*)(&WgT[e][d0]);
                acc[e] += xv[c].x * w.x + xv[c].y * w.y + xv[c].z * w.z + xv[c].w * w.w;
            }
        }
#pragma unroll
        for (int off = 1; off < 64; off <<= 1) {
#pragma unroll
            for (int e = 0; e < E_; ++e) acc[e] += __shfl_xor(acc[e], off, 64);
        }

        if (lane == 0) {
            // top-2, lowest-index-first on ties (matches jax.lax.top_k)
            float best = acc[0]; int bi = 0;
#pragma unroll
            for (int e = 1; e < E_; ++e) if (acc[e] > best) { best = acc[e]; bi = e; }
            float sec = -INFINITY; int si = 0;
#pragma unroll
            for (int e = 0; e < E_; ++e) if (e != bi && acc[e] > sec) { sec = acc[e]; si = e; }
            float s = best + sec + 1e-9f;
            route[token] = bi | (si << 8);
            gpair[token] = make_float2(best / s, sec / s);
        }
    }
}

// ---------------------------------------------------------------------------
// Kernel 1b: deterministic stream compaction, one block per (t,e) group.
// Ballot + popcount prefix; zero atomics; ascending-token order preserved.
// ---------------------------------------------------------------------------
__global__ __launch_bounds__(256) void build_lists(
    const int* __restrict__ route, const float2* __restrict__ gpair,
    int* __restrict__ toklist, float* __restrict__ gatelist,
    int* __restrict__ counts)
{
    int g = blockIdx.x;              // t*8 + e
    int t = g >> 3, e = g & 7;
    int tid = threadIdx.x;
    int wave = tid >> 6, lane = tid & 63;

    __shared__ int waveSum[4];
    __shared__ int base;
    if (tid == 0) base = 0;

    for (int c = 0; c < N_; c += 256) {
        int n = c + tid;
        int r = route[t * N_ + n];
        int e0 = r & 255, e1 = (r >> 8) & 255;
        bool sel = (e0 == e) || (e1 == e);
        unsigned long long b = __ballot(sel);
        int pre  = __popcll(b & ((1ull << lane) - 1ull));
        if (lane == 0) waveSum[wave] = __popcll(b);
        __syncthreads();             // waveSum + previous base update visible
        int woff = 0;
#pragma unroll
        for (int w = 0; w < 4; ++w) woff += (w < wave) ? waveSum[w] : 0;
        int total = waveSum[0] + waveSum[1] + waveSum[2] + waveSum[3];
        if (sel) {
            int p = base + woff + pre;
            toklist[g * N_ + p] = n;
            float2 gp = gpair[t * N_ + n];
            gatelist[g * N_ + p] = (e0 == e) ? gp.x : gp.y;
        }
        __syncthreads();             // everyone read base before tid0 bumps it
        if (tid == 0) base += total;
    }
    __syncthreads();
    if (tid == 0) counts[g] = base;
}

// ---------------------------------------------------------------------------
// Kernel 2: We fp32 [e][d][o] -> bf16 packed [(e*8+o/128)*128 + o%128][d].
// LDS transpose: coalesced 256B-segment reads AND writes.
// Block = 256 threads, tile = 64 o x 128 d. Grid = E * (O/64) * (D/128).
// ---------------------------------------------------------------------------
__global__ __launch_bounds__(256) void pack_kernel(
    const float* __restrict__ We, unsigned short* __restrict__ Wbp)
{
    __shared__ __align__(16) unsigned short P[64 * 136];

    int b = blockIdx.x;
    int e  = b >> 7;
    int oy = (b & 127) >> 3;   // 0..15
    int dz = b & 7;            // 0..7
    int o0 = oy * 64, d0 = dz * 128;
    int tid = threadIdx.x;

#pragma unroll
    for (int r = 0; r < 32; ++r) {
        int lin = r * 256 + tid;
        int dd = lin >> 6, oo = lin & 63;
        P[oo * 136 + dd] = f2bf(We[((size_t)(e * D_ + d0 + dd)) * O_ + o0 + oo]);
    }
    __syncthreads();

#pragma unroll
    for (int w = 0; w < 4; ++w) {
        int ci = w * 256 + tid;      // 1024 16B-chunks
        int oo = ci >> 4, dc = ci & 15;
        uint4 v = *(const uint4*)&P[oo * 136 + dc * 8];
        int o = o0 + oo;
        int ot = o >> 7, nn = o & 127;
        unsigned short* dst =
            Wbp + ((size_t)((e * 8 + ot) * 128 + nn)) * D_ + d0 + dc * 8;
        *(uint4*)dst = v;
    }
}

// ---------------------------------------------------------------------------
// Kernel 3: grouped GEMM, m97 structure. 128x128x32 tile, 4 waves x (4x4)
// mfma_f32_16x16x32_bf16, global_load_lds width=16, unpadded [row][32] LDS.
// XCD swizzle: m-tiles sharing a B-tile land on the same XCD's L2.
// Epilogue: gate-weighted fp32 atomicAdd (exactly 2 adds per out element).
// ---------------------------------------------------------------------------
__global__ __launch_bounds__(256) void moe_gemm(
    const unsigned short* __restrict__ xb,   // [T*N][D] bf16
    const unsigned short* __restrict__ Wbp,  // [(e*8+ot)*128+n][D] bf16
    const int* __restrict__ toklist, const float* __restrict__ gatelist,
    const int* __restrict__ counts, float* __restrict__ out)
{
    // flat id -> (m-tile, o-tile, group) with XCD affinity: xcd = lin & 7
    int lin = blockIdx.x + (blockIdx.y << 5) + (blockIdx.z << 8);  // 0..4095
    int xcd = lin & 7, slot = lin >> 3;       // 512 slots per XCD
    int mt = slot & 31;
    int pr = xcd * 16 + (slot >> 5);          // 0..127 = (ot, g) pair
    int ot = pr & 7;
    int g  = pr >> 3;                         // t*8 + e
    int t  = g >> 3;

    int cnt = counts[g];
    int m0 = mt * BM;
    if (m0 >= cnt) return;

    __shared__ __align__(16) unsigned short As[BM * 32];  // 8 KB
    __shared__ __align__(16) unsigned short Bs[BN * 32];  // 8 KB
    __shared__ int   tokS[BM];
    __shared__ float gateS[BM];

    int tid = threadIdx.x;
    if (tid < BM) {
        int r = m0 + tid;
        tokS[tid]  = (r < cnt) ? toklist[g * N_ + r]  : -1;
        gateS[tid] = (r < cnt) ? gatelist[g * N_ + r] : 0.f;
    }
    __syncthreads();

    int wave = tid >> 6, lane = tid & 63;
    // staging: wave w loads chunks 2w, 2w+1 of A and of B (16 rows/chunk)
    int lr = lane >> 2;          // row within chunk
    int lc = (lane & 3) * 8;     // short offset within row
    int c0 = wave * 2, c1 = c0 + 1;
    int ar0 = c0 * 16 + lr, ar1 = c1 * 16 + lr;
    int tok0 = max(tokS[ar0], 0), tok1 = max(tokS[ar1], 0);  // junk rows masked in epilogue
    const unsigned short* ag0 = xb + ((size_t)(t * N_ + tok0)) * D_ + lc;
    const unsigned short* ag1 = xb + ((size_t)(t * N_ + tok1)) * D_ + lc;
    const unsigned short* wb  = Wbp + ((size_t)((g & 7) * 8 + ot) * 128) * D_;
    const unsigned short* bg0 = wb + (size_t)ar0 * D_ + lc;
    const unsigned short* bg1 = wb + (size_t)ar1 * D_ + lc;
    unsigned short* la0 = &As[c0 * 16 * 32];  // wave-uniform LDS bases
    unsigned short* la1 = &As[c1 * 16 * 32];
    unsigned short* lb0 = &Bs[c0 * 16 * 32];
    unsigned short* lb1 = &Bs[c1 * 16 * 32];

    int wm = (wave & 1) * 64, wn = (wave >> 1) * 64;
    int fr = lane & 15, q = lane >> 4;

    f32x4 acc[4][4];
#pragma unroll
    for (int mi = 0; mi < 4; ++mi)
#pragma unroll
        for (int ni = 0; ni < 4; ++ni) acc[mi][ni] = (f32x4){0.f, 0.f, 0.f, 0.f};

    for (int k0 = 0; k0 < D_; k0 += BK) {
        gld16(ag0 + k0, la0);
        gld16(ag1 + k0, la1);
        gld16(bg0 + k0, lb0);
        gld16(bg1 + k0, lb1);
        __syncthreads();   // drains vmcnt (loads landed) + all waves staged

        short8 af[4], bf[4];
#pragma unroll
        for (int mi = 0; mi < 4; ++mi)
            af[mi] = *(const short8*)(&As[(wm + mi * 16 + fr) * 32 + q * 8]);
#pragma unroll
        for (int ni = 0; ni < 4; ++ni)
            bf[ni] = *(const short8*)(&Bs[(wn + ni * 16 + fr) * 32 + q * 8]);
#pragma unroll
        for (int mi = 0; mi < 4; ++mi)
#pragma unroll
            for (int ni = 0; ni < 4; ++ni)
                acc[mi][ni] = __builtin_amdgcn_mfma_f32_16x16x32_bf16(
                    af[mi], bf[ni], acc[mi][ni], 0, 0, 0);
        __syncthreads();   // frags consumed before next stage overwrites
    }

    // epilogue: C/D layout col = lane&15, row = q*4 + reg  [m89/m91]
    float* outb = out + (size_t)t * N_ * O_;
    int ncol = ot * 128 + wn + fr;
#pragma unroll
    for (int mi = 0; mi < 4; ++mi) {
#pragma unroll
        for (int r = 0; r < 4; ++r) {
            int ml = wm + mi * 16 + q * 4 + r;
            int tok = tokS[ml];
            if (tok >= 0) {
                float gate = gateS[ml];
#pragma unroll
                for (int ni = 0; ni < 4; ++ni)
                    atomicAdd(&outb[(size_t)tok * O_ + ncol + ni * 16],
                              gate * acc[mi][ni][r]);
            }
        }
    }
}

// ---------------------------------------------------------------------------
extern "C" void kernel_launch(void* const* d_in, const int* in_sizes, int n_in,
                              void* d_out, int out_size, void* d_ws, size_t ws_size,
                              hipStream_t stream)
{
    const float* x  = (const float*)d_in[0];
    const float* Wg = (const float*)d_in[1];
    const float* We = (const float*)d_in[2];
    float* out = (float*)d_out;

    char* ws = (char*)d_ws;
    unsigned short* xb   = (unsigned short*)(ws);               // 16,777,216 B
    unsigned short* Wbp  = (unsigned short*)(ws + 16777216);    // 16,777,216 B
    int*   toklist       = (int*)  (ws + 33554432);             //    262,144 B
    float* gatelist      = (float*)(ws + 33816576);             //    262,144 B
    int*   counts        = (int*)  (ws + 34078720);             //        256 B
    int*   route         = (int*)  (ws + 34078976);             //     32,768 B
    float2* gpair        = (float2*)(ws + 34111744);            //     65,536 B

    hipMemsetAsync(out, 0, (size_t)T_ * N_ * O_ * sizeof(float), stream);

    gate_kernel<<<(T_ * N_) / 16, 256, 0, stream>>>(x, Wg, xb, route, gpair);
    build_lists<<<T_ * E_, 256, 0, stream>>>(route, gpair, toklist, gatelist, counts);
    pack_kernel<<<E_ * (O_ / 64) * (D_ / 128), 256, 0, stream>>>(We, Wbp);
    moe_gemm<<<dim3(N_ / BM, O_ / BN, T_ * E_), 256, 0, stream>>>(
        xb, Wbp, toklist, gatelist, counts, out);
}

// Round 5
// 203.220 us; speedup vs baseline: 2.5540x; 1.0727x over previous
//
#include <hip/hip_runtime.h>
#include <hip/hip_bf16.h>
#include <stdint.h>

#define T_ 2
#define N_ 4096
#define D_ 1024
#define E_ 8
#define O_ 1024

#define BM 128
#define BN 128
#define BK 32   // K elements per LDS tile; unpadded rows (global_load_lds needs base+lane*16)

typedef __attribute__((ext_vector_type(8))) short short8;
typedef __attribute__((ext_vector_type(4))) float f32x4;

#define AS1 __attribute__((address_space(1)))
#define AS3 __attribute__((address_space(3)))

// async global->LDS, 16B per lane; LDS dest = base + lane*16 (wave-uniform base)
__device__ inline void gld16(const unsigned short* g, unsigned short* l) {
    __builtin_amdgcn_global_load_lds((const AS1 unsigned int*)g,
                                     (AS3 unsigned int*)l, 16, 0, 0);
}

__device__ inline unsigned short f2bf(float f) {
    union { float f; unsigned u; } v; v.f = f;
    unsigned r = v.u + 0x7fff + ((v.u >> 16) & 1);  // RNE
    return (unsigned short)(r >> 16);
}

// ---------------------------------------------------------------------------
// Kernel 1: gating + x->bf16. No atomics (R3 lesson: 16K atomics on one line
// = 195 us). 32 tokens/block to amortize the 32 KB Wg->LDS fill. Grid=T*N/32.
// ---------------------------------------------------------------------------
__global__ __launch_bounds__(256) void gate_kernel(
    const float* __restrict__ x, const float* __restrict__ Wg,
    unsigned short* __restrict__ xb,
    int* __restrict__ route, float2* __restrict__ gpair)
{
    __shared__ __align__(16) float WgT[E_][D_];   // 32 KB

    int tid = threadIdx.x;
    int wave = tid >> 6, lane = tid & 63;
    int token0 = blockIdx.x * 32;
    int t = token0 >> 12;                 // 32 consecutive tokens share t
    const float* wgb = Wg + (size_t)t * D_ * E_;

#pragma unroll
    for (int r = 0; r < 8; ++r) {
        int f = r * 1024 + tid * 4;       // flat Wg index; (d=f>>3, e=f&7)
        float4 v = *(const float4*)(wgb + f);
        WgT[f & 7][f >> 3]             = v.x;
        WgT[(f + 1) & 7][(f + 1) >> 3] = v.y;
        WgT[(f + 2) & 7][(f + 2) >> 3] = v.z;
        WgT[(f + 3) & 7][(f + 3) >> 3] = v.w;
    }
    __syncthreads();

    for (int tl = 0; tl < 8; ++tl) {
        int token = token0 + wave * 8 + tl;
        const float* xrow = x + (size_t)token * D_;

        float4 xv[4];
#pragma unroll
        for (int c = 0; c < 4; ++c)
            xv[c] = *(const float4*)(xrow + c * 256 + lane * 4);

        float acc[E_] = {0.f, 0.f, 0.f, 0.f, 0.f, 0.f, 0.f, 0.f};
#pragma unroll
        for (int c = 0; c < 4; ++c) {
            int d0 = c * 256 + lane * 4;
            unsigned lo = f2bf(xv[c].x) | ((unsigned)f2bf(xv[c].y) << 16);
            unsigned hi = f2bf(xv[c].z) | ((unsigned)f2bf(xv[c].w) << 16);
            *(uint2*)(&xb[(size_t)token * D_ + d0]) = make_uint2(lo, hi);
#pragma unroll
            for (int e = 0; e < E_; ++e) {
                float4 w = *(const float4*)(&WgT[e][d0]);
                acc[e] += xv[c].x * w.x + xv[c].y * w.y + xv[c].z * w.z + xv[c].w * w.w;
            }
        }
#pragma unroll
        for (int off = 1; off < 64; off <<= 1) {
#pragma unroll
            for (int e = 0; e < E_; ++e) acc[e] += __shfl_xor(acc[e], off, 64);
        }

        if (lane == 0) {
            // top-2, lowest-index-first on ties (matches jax.lax.top_k)
            float best = acc[0]; int bi = 0;
#pragma unroll
            for (int e = 1; e < E_; ++e) if (acc[e] > best) { best = acc[e]; bi = e; }
            float sec = -INFINITY; int si = 0;
#pragma unroll
            for (int e = 0; e < E_; ++e) if (e != bi && acc[e] > sec) { sec = acc[e]; si = e; }
            float s = best + sec + 1e-9f;
            route[token] = bi | (si << 8);
            gpair[token] = make_float2(best / s, sec / s);
        }
    }
}

// ---------------------------------------------------------------------------
// Kernel 1b: deterministic stream compaction, one block per (t,e) group.
// toklist entry = n | (slot<<16); slot = 0 if e is token's primary expert.
// ---------------------------------------------------------------------------
__global__ __launch_bounds__(256) void build_lists(
    const int* __restrict__ route, const float2* __restrict__ gpair,
    int* __restrict__ toklist, float* __restrict__ gatelist,
    int* __restrict__ counts)
{
    int g = blockIdx.x;              // t*8 + e
    int t = g >> 3, e = g & 7;
    int tid = threadIdx.x;
    int wave = tid >> 6, lane = tid & 63;

    __shared__ int waveSum[4];
    __shared__ int base;
    if (tid == 0) base = 0;

    for (int c = 0; c < N_; c += 256) {
        int n = c + tid;
        int r = route[t * N_ + n];
        int e0 = r & 255, e1 = (r >> 8) & 255;
        bool sel = (e0 == e) || (e1 == e);
        unsigned long long b = __ballot(sel);
        int pre  = __popcll(b & ((1ull << lane) - 1ull));
        if (lane == 0) waveSum[wave] = __popcll(b);
        __syncthreads();
        int woff = 0;
#pragma unroll
        for (int w = 0; w < 4; ++w) woff += (w < wave) ? waveSum[w] : 0;
        int total = waveSum[0] + waveSum[1] + waveSum[2] + waveSum[3];
        if (sel) {
            int p = base + woff + pre;
            int slot = (e0 == e) ? 0 : 1;
            toklist[g * N_ + p] = n | (slot << 16);
            float2 gp = gpair[t * N_ + n];
            gatelist[g * N_ + p] = (e0 == e) ? gp.x : gp.y;
        }
        __syncthreads();
        if (tid == 0) base += total;
    }
    __syncthreads();
    if (tid == 0) counts[g] = base;
}

// ---------------------------------------------------------------------------
// Kernel 2: We fp32 [e][d][o] -> bf16 packed [(e*8+o/128)*128 + o%128][d].
// ---------------------------------------------------------------------------
__global__ __launch_bounds__(256) void pack_kernel(
    const float* __restrict__ We, unsigned short* __restrict__ Wbp)
{
    __shared__ __align__(16) unsigned short P[64 * 136];

    int b = blockIdx.x;
    int e  = b >> 7;
    int oy = (b & 127) >> 3;   // 0..15
    int dz = b & 7;            // 0..7
    int o0 = oy * 64, d0 = dz * 128;
    int tid = threadIdx.x;

#pragma unroll
    for (int r = 0; r < 32; ++r) {
        int lin = r * 256 + tid;
        int dd = lin >> 6, oo = lin & 63;
        P[oo * 136 + dd] = f2bf(We[((size_t)(e * D_ + d0 + dd)) * O_ + o0 + oo]);
    }
    __syncthreads();

#pragma unroll
    for (int w = 0; w < 4; ++w) {
        int ci = w * 256 + tid;      // 1024 16B-chunks
        int oo = ci >> 4, dc = ci & 15;
        uint4 v = *(const uint4*)&P[oo * 136 + dc * 8];
        int o = o0 + oo;
        int ot = o >> 7, nn = o & 127;
        unsigned short* dst =
            Wbp + ((size_t)((e * 8 + ot) * 128 + nn)) * D_ + d0 + dc * 8;
        *(uint4*)dst = v;
    }
}

// ---------------------------------------------------------------------------
// Kernel 3: grouped GEMM. Round 5: epilogue stores bf16 contribution into
// the low/high u16 half of out's own fp32 word (slot trick) -- NO atomics
// (round-4 counters: 16.8M atomicAdds = WRITE_SIZE 67MB = the 92us limiter).
// Byte-enabled 2B stores from different blocks never collide; combine_kernel
// sums the halves afterwards.
// ---------------------------------------------------------------------------
__global__ __launch_bounds__(256) void moe_gemm(
    const unsigned short* __restrict__ xb,   // [T*N][D] bf16
    const unsigned short* __restrict__ Wbp,  // [(e*8+ot)*128+n][D] bf16
    const int* __restrict__ toklist, const float* __restrict__ gatelist,
    const int* __restrict__ counts, float* __restrict__ out)
{
    // flat id -> (m-tile, o-tile, group) with XCD affinity: xcd = lin & 7
    int lin = blockIdx.x + (blockIdx.y << 5) + (blockIdx.z << 8);  // 0..4095
    int xcd = lin & 7, slot_ = lin >> 3;      // 512 slots per XCD
    int mt = slot_ & 31;
    int pr = xcd * 16 + (slot_ >> 5);         // 0..127 = (ot, g) pair
    int ot = pr & 7;
    int g  = pr >> 3;                         // t*8 + e
    int t  = g >> 3;

    int cnt = counts[g];
    int m0 = mt * BM;
    if (m0 >= cnt) return;

    __shared__ __align__(16) unsigned short As[BM * 32];  // 8 KB
    __shared__ __align__(16) unsigned short Bs[BN * 32];  // 8 KB
    __shared__ int   tokS[BM];
    __shared__ float gateS[BM];

    int tid = threadIdx.x;
    if (tid < BM) {
        int r = m0 + tid;
        tokS[tid]  = (r < cnt) ? toklist[g * N_ + r]  : -1;
        gateS[tid] = (r < cnt) ? gatelist[g * N_ + r] : 0.f;
    }
    __syncthreads();

    int wave = tid >> 6, lane = tid & 63;
    int lr = lane >> 2;          // row within 16-row chunk
    int lc = (lane & 3) * 8;     // short offset within row
    int c0 = wave * 2, c1 = c0 + 1;
    int ar0 = c0 * 16 + lr, ar1 = c1 * 16 + lr;
    int tok0 = max(tokS[ar0], 0) & 0xFFFF;   // junk rows masked in epilogue
    int tok1 = max(tokS[ar1], 0) & 0xFFFF;
    const unsigned short* ag0 = xb + ((size_t)(t * N_ + tok0)) * D_ + lc;
    const unsigned short* ag1 = xb + ((size_t)(t * N_ + tok1)) * D_ + lc;
    const unsigned short* wb  = Wbp + ((size_t)((g & 7) * 8 + ot) * 128) * D_;
    const unsigned short* bg0 = wb + (size_t)ar0 * D_ + lc;
    const unsigned short* bg1 = wb + (size_t)ar1 * D_ + lc;
    unsigned short* la0 = &As[c0 * 16 * 32];  // wave-uniform LDS bases
    unsigned short* la1 = &As[c1 * 16 * 32];
    unsigned short* lb0 = &Bs[c0 * 16 * 32];
    unsigned short* lb1 = &Bs[c1 * 16 * 32];

    int wm = (wave & 1) * 64, wn = (wave >> 1) * 64;
    int fr = lane & 15, q = lane >> 4;

    f32x4 acc[4][4];
#pragma unroll
    for (int mi = 0; mi < 4; ++mi)
#pragma unroll
        for (int ni = 0; ni < 4; ++ni) acc[mi][ni] = (f32x4){0.f, 0.f, 0.f, 0.f};

    for (int k0 = 0; k0 < D_; k0 += BK) {
        gld16(ag0 + k0, la0);
        gld16(ag1 + k0, la1);
        gld16(bg0 + k0, lb0);
        gld16(bg1 + k0, lb1);
        __syncthreads();   // drains vmcnt (loads landed) + all waves staged

        short8 af[4], bf[4];
#pragma unroll
        for (int mi = 0; mi < 4; ++mi)
            af[mi] = *(const short8*)(&As[(wm + mi * 16 + fr) * 32 + q * 8]);
#pragma unroll
        for (int ni = 0; ni < 4; ++ni)
            bf[ni] = *(const short8*)(&Bs[(wn + ni * 16 + fr) * 32 + q * 8]);
#pragma unroll
        for (int mi = 0; mi < 4; ++mi)
#pragma unroll
            for (int ni = 0; ni < 4; ++ni)
                acc[mi][ni] = __builtin_amdgcn_mfma_f32_16x16x32_bf16(
                    af[mi], bf[ni], acc[mi][ni], 0, 0, 0);
        __syncthreads();   // frags consumed before next stage overwrites
    }

    // epilogue: C/D layout col = lane&15, row = q*4 + reg  [m89/m91]
    float* outb = out + (size_t)t * N_ * O_;
    int ncol = ot * 128 + wn + fr;
#pragma unroll
    for (int mi = 0; mi < 4; ++mi) {
#pragma unroll
        for (int r = 0; r < 4; ++r) {
            int ml = wm + mi * 16 + q * 4 + r;
            int ent = tokS[ml];
            if (ent >= 0) {
                int tok  = ent & 0xFFFF;
                int slot = ent >> 16;
                float gate = gateS[ml];
#pragma unroll
                for (int ni = 0; ni < 4; ++ni) {
                    unsigned short* p =
                        (unsigned short*)(outb + (size_t)tok * O_ + ncol + ni * 16);
                    p[slot] = f2bf(gate * acc[mi][ni][r]);
                }
            }
        }
    }
}

// ---------------------------------------------------------------------------
// Kernel 4: combine the two bf16 slot halves of each out word into fp32.
// In-place: u32 -> bf16(lo) + bf16(hi) -> fp32 store. 4 words/thread.
// ---------------------------------------------------------------------------
__global__ __launch_bounds__(256) void combine_kernel(float* __restrict__ out)
{
    size_t i = ((size_t)blockIdx.x * 256 + threadIdx.x) * 4;
    unsigned* po = (unsigned*)out;
    uint4 v = *(uint4*)(po + i);
    float4 r;
    union { unsigned u; float f; } a, b;
#define CMB(comp, src) a.u = (src) << 16; b.u = (src) & 0xFFFF0000u; comp = a.f + b.f
    CMB(r.x, v.x); CMB(r.y, v.y); CMB(r.z, v.z); CMB(r.w, v.w);
#undef CMB
    *(float4*)(out + i) = r;
}

// ---------------------------------------------------------------------------
extern "C" void kernel_launch(void* const* d_in, const int* in_sizes, int n_in,
                              void* d_out, int out_size, void* d_ws, size_t ws_size,
                              hipStream_t stream)
{
    const float* x  = (const float*)d_in[0];
    const float* Wg = (const float*)d_in[1];
    const float* We = (const float*)d_in[2];
    float* out = (float*)d_out;

    char* ws = (char*)d_ws;
    unsigned short* xb   = (unsigned short*)(ws);               // 16,777,216 B
    unsigned short* Wbp  = (unsigned short*)(ws + 16777216);    // 16,777,216 B
    int*   toklist       = (int*)  (ws + 33554432);             //    262,144 B
    float* gatelist      = (float*)(ws + 33816576);             //    262,144 B
    int*   counts        = (int*)  (ws + 34078720);             //        256 B
    int*   route         = (int*)  (ws + 34078976);             //     32,768 B
    float2* gpair        = (float2*)(ws + 34111744);            //     65,536 B

    gate_kernel<<<(T_ * N_) / 32, 256, 0, stream>>>(x, Wg, xb, route, gpair);
    build_lists<<<T_ * E_, 256, 0, stream>>>(route, gpair, toklist, gatelist, counts);
    pack_kernel<<<E_ * (O_ / 64) * (D_ / 128), 256, 0, stream>>>(We, Wbp);
    moe_gemm<<<dim3(N_ / BM, O_ / BN, T_ * E_), 256, 0, stream>>>(
        xb, Wbp, toklist, gatelist, counts, out);
    combine_kernel<<<((size_t)T_ * N_ * O_) / (256 * 4), 256, 0, stream>>>(out);
}